// Round 1
// baseline (2090.531 us; speedup 1.0000x reference)
//
#include <hip/hip_runtime.h>
#include <math.h>

#define BATCH 16
#define HW 262144          // 512*512
#define KSEL 26214         // int(0.1 * 262144)
#define MCAND 80           // TOP_K * CAND_MULT
#define TOPK 5
#define CAP 2048

__device__ __forceinline__ float2 cplx_mul(float2 a, float2 b) {
    return make_float2(a.x * b.x - a.y * b.y, a.x * b.y + a.y * b.x);
}

// In-LDS Stockham radix-2 FFT, N=512, 256 threads (1 butterfly/thread/stage).
// dir = -1 forward, +1 inverse (unnormalized). Caller must __syncthreads()
// after filling s0. Returns pointer to buffer holding the result.
__device__ float2* fft512(float2* s0, float2* s1, int t, float dir) {
    float2* src = s0;
    float2* dst = s1;
    #pragma unroll
    for (int Ns = 1; Ns < 512; Ns <<= 1) {
        float2 a = src[t];
        float2 b = src[t + 256];
        int r = t & (Ns - 1);
        float ang = dir * (6.283185307179586f * (float)r / (float)(2 * Ns));
        float sn, cs;
        sincosf(ang, &sn, &cs);
        float2 wb = make_float2(cs * b.x - sn * b.y, cs * b.y + sn * b.x);
        int d = ((t - r) << 1) + r;
        dst[d]      = make_float2(a.x + wb.x, a.y + wb.y);
        dst[d + Ns] = make_float2(a.x - wb.x, a.y - wb.y);
        float2* tm = src; src = dst; dst = tm;
        __syncthreads();
    }
    return src;
}

// K1: window + forward FFT along W. One block per (b, h) row.
__global__ void k_win_rowfft(const float* __restrict__ img, float2* __restrict__ A) {
    __shared__ float2 s0[512];
    __shared__ float2 s1[512];
    int row = blockIdx.x;           // b*512 + h
    int h = row & 511;
    int t = threadIdx.x;
    float wr = 0.5f * (1.0f - cosf(6.283185307179586f * (float)h / 511.0f));
    const float* p = img + (size_t)row * 512;
    for (int i = t; i < 512; i += 256) {
        float wc = 0.5f * (1.0f - cosf(6.283185307179586f * (float)i / 511.0f));
        s0[i] = make_float2(p[i] * wr * wc, 0.0f);
    }
    __syncthreads();
    float2* res = fft512(s0, s1, t, -1.0f);
    float2* out = A + (size_t)row * 512;
    for (int i = t; i < 512; i += 256) out[i] = res[i];
}

// Generic in-place row FFT. PHASE=1: phase-only normalize on store.
template <int PHASE>
__global__ void k_rowfft(float2* __restrict__ X, float dir) {
    __shared__ float2 s0[512];
    __shared__ float2 s1[512];
    int row = blockIdx.x;
    int t = threadIdx.x;
    float2* p = X + (size_t)row * 512;
    for (int i = t; i < 512; i += 256) s0[i] = p[i];
    __syncthreads();
    float2* res = fft512(s0, s1, t, dir);
    for (int i = t; i < 512; i += 256) {
        float2 v = res[i];
        if (PHASE) {
            float m = sqrtf(v.x * v.x + v.y * v.y);
            if (m > 0.0f) { v.x /= m; v.y /= m; }
            else          { v = make_float2(1.0f, 0.0f); }
        }
        p[i] = v;
    }
}

// Final inverse row FFT + 1/(H*W) scaling + |.|^2
__global__ void k_rowfft_mag(const float2* __restrict__ X, float* __restrict__ sal) {
    __shared__ float2 s0[512];
    __shared__ float2 s1[512];
    int row = blockIdx.x;
    int t = threadIdx.x;
    const float2* p = X + (size_t)row * 512;
    for (int i = t; i < 512; i += 256) s0[i] = p[i];
    __syncthreads();
    float2* res = fft512(s0, s1, t, 1.0f);
    float* out = sal + (size_t)row * 512;
    const float s = 3.814697265625e-06f;   // 1/262144, exact
    for (int i = t; i < 512; i += 256) {
        float re = res[i].x * s, im = res[i].y * s;
        out[i] = re * re + im * im;
    }
}

// Per-image 512x512 complex transpose, 32x32 tiles.
__global__ void k_transpose(const float2* __restrict__ in, float2* __restrict__ out) {
    __shared__ float2 tile[32][33];
    int b = blockIdx.z;
    int x0 = blockIdx.x * 32, y0 = blockIdx.y * 32;
    const float2* ib = in + (size_t)b * HW;
    float2* ob = out + (size_t)b * HW;
    int tx = threadIdx.x, ty = threadIdx.y;
    #pragma unroll
    for (int i = 0; i < 32; i += 8)
        tile[ty + i][tx] = ib[(size_t)(y0 + ty + i) * 512 + x0 + tx];
    __syncthreads();
    #pragma unroll
    for (int i = 0; i < 32; i += 8)
        ob[(size_t)(x0 + ty + i) * 512 + y0 + tx] = tile[tx][ty + i];
}

// Gaussian blur, sigma=1, 5-tap, zero padding. Coefficients (double-derived).
#define GW0 0.05448868454964294f
#define GW1 0.24420134200323332f
#define GW2 0.40261994689424746f

__global__ void k_hblur(const float* __restrict__ in, float* __restrict__ out) {
    int i = blockIdx.x * blockDim.x + threadIdx.x;
    if (i >= BATCH * HW) return;
    int x = i & 511;
    float acc = GW2 * in[i];
    if (x >= 1)   acc += GW1 * in[i - 1];
    if (x >= 2)   acc += GW0 * in[i - 2];
    if (x <= 510) acc += GW1 * in[i + 1];
    if (x <= 509) acc += GW0 * in[i + 2];
    out[i] = acc;
}

__global__ void k_vblur(const float* __restrict__ in, float* __restrict__ out) {
    int i = blockIdx.x * blockDim.x + threadIdx.x;
    if (i >= BATCH * HW) return;
    int y = (i >> 9) & 511;
    float acc = GW2 * in[i];
    if (y >= 1)   acc += GW1 * in[i - 512];
    if (y >= 2)   acc += GW0 * in[i - 1024];
    if (y <= 510) acc += GW1 * in[i + 512];
    if (y <= 509) acc += GW0 * in[i + 1024];
    out[i] = acc;
}

// Per-image min/max over blurred (pre-mask) saliency.
__global__ void k_minmax(const float* __restrict__ sal, float* __restrict__ mn, float* __restrict__ mx) {
    __shared__ float smn[1024];
    __shared__ float smx[1024];
    int b = blockIdx.x, t = threadIdx.x;
    const float* p = sal + (size_t)b * HW;
    float lmn = INFINITY, lmx = -INFINITY;
    for (int i = t; i < HW; i += 1024) {
        float v = p[i];
        lmn = fminf(lmn, v);
        lmx = fmaxf(lmx, v);
    }
    smn[t] = lmn; smx[t] = lmx;
    __syncthreads();
    for (int s = 512; s > 0; s >>= 1) {
        if (t < s) { smn[t] = fminf(smn[t], smn[t + s]); smx[t] = fmaxf(smx[t], smx[t + s]); }
        __syncthreads();
    }
    if (t == 0) { mn[b] = smn[0]; mx[b] = smx[0]; }
}

// Normalize + border mask -> final saliency (written into d_out).
__global__ void k_norm(const float* __restrict__ in, const float* __restrict__ mn,
                       const float* __restrict__ mx, float* __restrict__ out) {
    int i = blockIdx.x * blockDim.x + threadIdx.x;
    if (i >= BATCH * HW) return;
    int b = i >> 18;
    int x = i & 511;
    int y = (i >> 9) & 511;
    float v = (in[i] - mn[b]) / (mx[b] - mn[b] + 1e-8f);
    bool inside = (x >= 12) && (x < 500) && (y >= 12) && (y < 500);
    out[i] = inside ? v : 0.0f;
}

// Exact KSEL-th largest value per image (radix-select on float bits; all vals >= 0).
__global__ void k_kth(const float* __restrict__ sal, float* __restrict__ thr) {
    __shared__ unsigned int hist[4096];
    __shared__ unsigned int sprefix;
    __shared__ int skrem;
    int b = blockIdx.x, t = threadIdx.x;
    const float* p = sal + (size_t)b * HW;
    if (t == 0) { sprefix = 0u; skrem = KSEL; }

    // Round 0: bits [31:20]
    for (int i = t; i < 4096; i += 256) hist[i] = 0u;
    __syncthreads();
    for (int i = t; i < HW; i += 256) {
        unsigned int u = __float_as_uint(p[i]);
        atomicAdd(&hist[u >> 20], 1u);
    }
    __syncthreads();
    if (t == 0) {
        int krem = skrem; unsigned int cum = 0; int d = 4095;
        for (; d >= 0; d--) { cum += hist[d]; if ((int)cum >= krem) break; }
        skrem = krem - (int)(cum - hist[d]);
        sprefix = (unsigned int)d;
    }
    __syncthreads();

    // Round 1: bits [19:8]
    for (int i = t; i < 4096; i += 256) hist[i] = 0u;
    __syncthreads();
    {
        unsigned int prefix = sprefix;
        for (int i = t; i < HW; i += 256) {
            unsigned int u = __float_as_uint(p[i]);
            if ((u >> 20) == prefix) atomicAdd(&hist[(u >> 8) & 4095u], 1u);
        }
    }
    __syncthreads();
    if (t == 0) {
        int krem = skrem; unsigned int cum = 0; int d = 4095;
        for (; d >= 0; d--) { cum += hist[d]; if ((int)cum >= krem) break; }
        skrem = krem - (int)(cum - hist[d]);
        sprefix = (sprefix << 12) | (unsigned int)d;
    }
    __syncthreads();

    // Round 2: bits [7:0]
    for (int i = t; i < 4096; i += 256) hist[i] = 0u;
    __syncthreads();
    {
        unsigned int prefix = sprefix;
        for (int i = t; i < HW; i += 256) {
            unsigned int u = __float_as_uint(p[i]);
            if ((u >> 8) == prefix) atomicAdd(&hist[u & 255u], 1u);
        }
    }
    __syncthreads();
    if (t == 0) {
        int krem = skrem; unsigned int cum = 0; int d = 255;
        for (; d >= 0; d--) { cum += hist[d]; if ((int)cum >= krem) break; }
        unsigned int bitsv = (sprefix << 8) | (unsigned int)d;
        thr[b] = fmaxf(__uint_as_float(bitsv), 0.1f);
    }
}

// Top-80 (value desc, index asc — lax.top_k tie rule) among sal >= thr,
// then greedy min-dist NMS; write coords + labels.
__global__ void k_select(const float* __restrict__ sal, const float* __restrict__ thr,
                         float* __restrict__ out) {
    __shared__ unsigned int hist[4096];
    __shared__ unsigned int sprefix;
    __shared__ int skrem;
    __shared__ int sfewer;
    __shared__ unsigned int scutoff;
    __shared__ float cval[CAP];
    __shared__ int   cidx[CAP];
    __shared__ int   ccnt;
    __shared__ float sv[MCAND];
    __shared__ int   si[MCAND];

    int b = blockIdx.x, t = threadIdx.x;
    const float* p = sal + (size_t)b * HW;
    float fthr = thr[b];
    unsigned int uthr = __float_as_uint(fthr);
    if (t == 0) { sprefix = 0u; skrem = MCAND; ccnt = 0; sfewer = 0; }

    // Round 0: bits [31:20], filtered by v >= thr
    for (int i = t; i < 4096; i += 256) hist[i] = 0u;
    __syncthreads();
    for (int i = t; i < HW; i += 256) {
        unsigned int u = __float_as_uint(p[i]);
        if (u >= uthr) atomicAdd(&hist[u >> 20], 1u);
    }
    __syncthreads();
    if (t == 0) {
        unsigned int total = 0;
        for (int d = 0; d < 4096; d++) total += hist[d];
        if ((int)total < MCAND) {
            sfewer = 1; scutoff = uthr;
        } else {
            int krem = skrem; unsigned int cum = 0; int d = 4095;
            for (; d >= 0; d--) { cum += hist[d]; if ((int)cum >= krem) break; }
            skrem = krem - (int)(cum - hist[d]);
            sprefix = (unsigned int)d;
        }
    }
    __syncthreads();

    if (!sfewer) {
        // Round 1: bits [19:8]
        for (int i = t; i < 4096; i += 256) hist[i] = 0u;
        __syncthreads();
        {
            unsigned int prefix = sprefix;
            for (int i = t; i < HW; i += 256) {
                unsigned int u = __float_as_uint(p[i]);
                if (u >= uthr && (u >> 20) == prefix) atomicAdd(&hist[(u >> 8) & 4095u], 1u);
            }
        }
        __syncthreads();
        if (t == 0) {
            int krem = skrem; unsigned int cum = 0; int d = 4095;
            for (; d >= 0; d--) { cum += hist[d]; if ((int)cum >= krem) break; }
            skrem = krem - (int)(cum - hist[d]);
            sprefix = (sprefix << 12) | (unsigned int)d;
        }
        __syncthreads();

        // Round 2: bits [7:0]
        for (int i = t; i < 4096; i += 256) hist[i] = 0u;
        __syncthreads();
        {
            unsigned int prefix = sprefix;
            for (int i = t; i < HW; i += 256) {
                unsigned int u = __float_as_uint(p[i]);
                if (u >= uthr && (u >> 8) == prefix) atomicAdd(&hist[u & 255u], 1u);
            }
        }
        __syncthreads();
        if (t == 0) {
            int krem = skrem; unsigned int cum = 0; int d = 255;
            for (; d >= 0; d--) { cum += hist[d]; if ((int)cum >= krem) break; }
            scutoff = (sprefix << 8) | (unsigned int)d;
        }
        __syncthreads();
    }

    // Collect all candidates with value >= cutoff (and >= thr)
    {
        unsigned int cutoff = scutoff;
        for (int i = t; i < HW; i += 256) {
            unsigned int u = __float_as_uint(p[i]);
            if (u >= cutoff && u >= uthr) {
                int pos = atomicAdd(&ccnt, 1);
                if (pos < CAP) { cval[pos] = p[i]; cidx[pos] = i; }
            }
        }
    }
    __syncthreads();
    int n = min(ccnt, CAP);
    int m = min(n, MCAND);

    // Rank by (value desc, index asc); scatter top-80 into sorted slots.
    for (int i = t; i < n; i += 256) {
        float vi = cval[i]; int ii = cidx[i];
        int rank = 0;
        for (int j = 0; j < n; j++) {
            float vj = cval[j];
            if (vj > vi || (vj == vi && cidx[j] < ii)) rank++;
        }
        if (rank < MCAND) { sv[rank] = vi; si[rank] = ii; }
    }
    __syncthreads();

    // Serial greedy NMS (matches the reference fori_loop exactly).
    if (t == 0) {
        float kx[TOPK], ky[TOPK];
        int cnt = 0;
        for (int i = 0; i < m; i++) {
            float x = (float)(si[i] & 511);
            float y = (float)(si[i] >> 9);
            bool near_kept = false;
            for (int j = 0; j < cnt; j++) {
                float dx = kx[j] - x, dy = ky[j] - y;
                if (dx * dx + dy * dy < 100.0f) near_kept = true;
            }
            if (!near_kept && cnt < TOPK) { kx[cnt] = x; ky[cnt] = y; cnt++; }
        }
        for (int j = 0; j < TOPK; j++) {
            out[b * 10 + 2 * j]     = (j < cnt) ? kx[j] : -1.0f;
            out[b * 10 + 2 * j + 1] = (j < cnt) ? ky[j] : -1.0f;
            out[160 + b * 5 + j]    = (j < cnt) ? 1.0f : -1.0f;
        }
    }
}

extern "C" void kernel_launch(void* const* d_in, const int* in_sizes, int n_in,
                              void* d_out, int out_size, void* d_ws, size_t ws_size,
                              hipStream_t stream) {
    const float* img = (const float*)d_in[0];
    float* out = (float*)d_out;
    char* ws = (char*)d_ws;

    // ws layout (bytes):
    //   [0, 32M)    : A  (complex, 16*512*512 float2) — later reused as hblur tmp (float)
    //   [32M, 64M)  : Bc (complex)                     — lo half reused as salraw, hi half as salb
    //   [64M, +192) : stats: thr[16], mn[16], mx[16]
    float2* A      = (float2*)ws;
    float2* Bc     = (float2*)(ws + 33554432UL);
    float*  salraw = (float*)(ws + 33554432UL);
    float*  tmp    = (float*)ws;
    float*  salb   = (float*)(ws + 50331648UL);
    float*  stats  = (float*)(ws + 67108864UL);
    float* thr = stats;
    float* mn  = stats + 16;
    float* mx  = stats + 32;
    float* salout = out + 240;   // sal region of d_out

    k_win_rowfft<<<dim3(8192), dim3(256), 0, stream>>>(img, A);
    k_transpose<<<dim3(16, 16, 16), dim3(32, 8), 0, stream>>>(A, Bc);
    k_rowfft<1><<<dim3(8192), dim3(256), 0, stream>>>(Bc, -1.0f);  // complete fwd 2D FFT + phase-only
    k_rowfft<0><<<dim3(8192), dim3(256), 0, stream>>>(Bc, 1.0f);   // inverse along H
    k_transpose<<<dim3(16, 16, 16), dim3(32, 8), 0, stream>>>(Bc, A);
    k_rowfft_mag<<<dim3(8192), dim3(256), 0, stream>>>(A, salraw); // inverse along W + |.|^2 / N^2
    k_hblur<<<dim3(16384), dim3(256), 0, stream>>>(salraw, tmp);
    k_vblur<<<dim3(16384), dim3(256), 0, stream>>>(tmp, salb);
    k_minmax<<<dim3(BATCH), dim3(1024), 0, stream>>>(salb, mn, mx);
    k_norm<<<dim3(16384), dim3(256), 0, stream>>>(salb, mn, mx, salout);
    k_kth<<<dim3(BATCH), dim3(256), 0, stream>>>(salout, thr);
    k_select<<<dim3(BATCH), dim3(256), 0, stream>>>(salout, thr, out);
}

// Round 2
// 512.904 us; speedup vs baseline: 4.0759x; 4.0759x over previous
//
#include <hip/hip_runtime.h>
#include <math.h>

#define BATCH 16
#define HW 262144          // 512*512
#define KSEL 26214         // int(0.1 * 262144)
#define MCAND 80           // TOP_K * CAND_MULT
#define TOPK 5
#define CAP 2048

// ---------------------------------------------------------------------------
// FFT: in-LDS Stockham radix-2, N=512, 256 threads (1 butterfly/thread/stage).
// dir = -1 forward, +1 inverse (unnormalized). Caller syncs after filling s0.
// Returns pointer to buffer holding the result (after 9 stages: the "other").
// ---------------------------------------------------------------------------
__device__ float2* fft512(float2* s0, float2* s1, int t, float dir) {
    float2* src = s0;
    float2* dst = s1;
    #pragma unroll
    for (int Ns = 1; Ns < 512; Ns <<= 1) {
        float2 a = src[t];
        float2 b = src[t + 256];
        int r = t & (Ns - 1);
        float ang = dir * (6.283185307179586f * (float)r / (float)(2 * Ns));
        float sn, cs;
        sincosf(ang, &sn, &cs);
        float2 wb = make_float2(cs * b.x - sn * b.y, cs * b.y + sn * b.x);
        int d = ((t - r) << 1) + r;
        dst[d]      = make_float2(a.x + wb.x, a.y + wb.y);
        dst[d + Ns] = make_float2(a.x - wb.x, a.y - wb.y);
        float2* tm = src; src = dst; dst = tm;
        __syncthreads();
    }
    return src;
}

// K1: window + forward FFT along W. One block per (b, h) row.
__global__ void k_win_rowfft(const float* __restrict__ img, float2* __restrict__ A) {
    __shared__ float2 s0[512];
    __shared__ float2 s1[512];
    int row = blockIdx.x;           // b*512 + h
    int h = row & 511;
    int t = threadIdx.x;
    float wr = 0.5f * (1.0f - cosf(6.283185307179586f * (float)h / 511.0f));
    const float* p = img + (size_t)row * 512;
    for (int i = t; i < 512; i += 256) {
        float wc = 0.5f * (1.0f - cosf(6.283185307179586f * (float)i / 511.0f));
        s0[i] = make_float2(p[i] * wr * wc, 0.0f);
    }
    __syncthreads();
    float2* res = fft512(s0, s1, t, -1.0f);
    float2* out = A + (size_t)row * 512;
    for (int i = t; i < 512; i += 256) out[i] = res[i];
}

// Fused: forward FFT along H (completing the 2D FFT) -> phase-only normalize
// -> inverse FFT along H. Data is transposed, so "rows" here are H-columns.
__global__ void k_phase(float2* __restrict__ X) {
    __shared__ float2 s0[512];
    __shared__ float2 s1[512];
    int row = blockIdx.x;
    int t = threadIdx.x;
    float2* p = X + (size_t)row * 512;
    for (int i = t; i < 512; i += 256) s0[i] = p[i];
    __syncthreads();
    float2* res = fft512(s0, s1, t, -1.0f);
    for (int i = t; i < 512; i += 256) {
        float2 v = res[i];
        float m = sqrtf(v.x * v.x + v.y * v.y);
        if (m > 0.0f) { v.x /= m; v.y /= m; }
        else          { v = make_float2(1.0f, 0.0f); }
        res[i] = v;
    }
    __syncthreads();
    float2* other = (res == s0) ? s1 : s0;
    float2* res2 = fft512(res, other, t, 1.0f);
    for (int i = t; i < 512; i += 256) p[i] = res2[i];
}

// Final inverse row FFT + 1/(H*W) scaling + |.|^2
__global__ void k_rowfft_mag(const float2* __restrict__ X, float* __restrict__ sal) {
    __shared__ float2 s0[512];
    __shared__ float2 s1[512];
    int row = blockIdx.x;
    int t = threadIdx.x;
    const float2* p = X + (size_t)row * 512;
    for (int i = t; i < 512; i += 256) s0[i] = p[i];
    __syncthreads();
    float2* res = fft512(s0, s1, t, 1.0f);
    float* out = sal + (size_t)row * 512;
    const float s = 3.814697265625e-06f;   // 1/262144, exact
    for (int i = t; i < 512; i += 256) {
        float re = res[i].x * s, im = res[i].y * s;
        out[i] = re * re + im * im;
    }
}

// Per-image 512x512 complex transpose, 32x32 tiles.
__global__ void k_transpose(const float2* __restrict__ in, float2* __restrict__ out) {
    __shared__ float2 tile[32][33];
    int b = blockIdx.z;
    int x0 = blockIdx.x * 32, y0 = blockIdx.y * 32;
    const float2* ib = in + (size_t)b * HW;
    float2* ob = out + (size_t)b * HW;
    int tx = threadIdx.x, ty = threadIdx.y;
    #pragma unroll
    for (int i = 0; i < 32; i += 8)
        tile[ty + i][tx] = ib[(size_t)(y0 + ty + i) * 512 + x0 + tx];
    __syncthreads();
    #pragma unroll
    for (int i = 0; i < 32; i += 8)
        ob[(size_t)(x0 + ty + i) * 512 + y0 + tx] = tile[tx][ty + i];
}

// Gaussian blur, sigma=1, 5-tap, zero padding.
#define GW0 0.05448868454964294f
#define GW1 0.24420134200323332f
#define GW2 0.40261994689424746f

__global__ void k_hblur(const float* __restrict__ in, float* __restrict__ out) {
    int i = blockIdx.x * blockDim.x + threadIdx.x;
    if (i >= BATCH * HW) return;
    int x = i & 511;
    float acc = GW2 * in[i];
    if (x >= 1)   acc += GW1 * in[i - 1];
    if (x >= 2)   acc += GW0 * in[i - 2];
    if (x <= 510) acc += GW1 * in[i + 1];
    if (x <= 509) acc += GW0 * in[i + 2];
    out[i] = acc;
}

// vblur + fused per-image min/max (uint atomics; all values >= 0).
__global__ void k_vblur(const float* __restrict__ in, float* __restrict__ out,
                        unsigned int* __restrict__ mnb, unsigned int* __restrict__ mxb) {
    __shared__ float smn[256];
    __shared__ float smx[256];
    int t = threadIdx.x;
    int i = blockIdx.x * 256 + t;
    int b = i >> 18;
    int y = (i >> 9) & 511;
    float acc = GW2 * in[i];
    if (y >= 1)   acc += GW1 * in[i - 512];
    if (y >= 2)   acc += GW0 * in[i - 1024];
    if (y <= 510) acc += GW1 * in[i + 512];
    if (y <= 509) acc += GW0 * in[i + 1024];
    out[i] = acc;
    smn[t] = acc; smx[t] = acc;
    __syncthreads();
    for (int s = 128; s > 0; s >>= 1) {
        if (t < s) { smn[t] = fminf(smn[t], smn[t + s]); smx[t] = fmaxf(smx[t], smx[t + s]); }
        __syncthreads();
    }
    if (t == 0) {
        atomicMin(&mnb[b], __float_as_uint(smn[0]));
        atomicMax(&mxb[b], __float_as_uint(smx[0]));
    }
}

// Normalize + border mask -> final saliency (written into d_out).
__global__ void k_norm(const float* __restrict__ in, const unsigned int* __restrict__ mnb,
                       const unsigned int* __restrict__ mxb, float* __restrict__ out) {
    int i = blockIdx.x * blockDim.x + threadIdx.x;
    if (i >= BATCH * HW) return;
    int b = i >> 18;
    int x = i & 511;
    int y = (i >> 9) & 511;
    float mn = __uint_as_float(mnb[b]);
    float mx = __uint_as_float(mxb[b]);
    float v = (in[i] - mn) / (mx - mn + 1e-8f);
    bool inside = (x >= 12) && (x < 500) && (y >= 12) && (y < 500);
    out[i] = inside ? v : 0.0f;
}

// ---------------------------------------------------------------------------
// Parallel 3-round radix select (bits 12/12/8) for BOTH k=26214 (threshold)
// and k=80 (candidate cutoff), sharing the same histogram passes.
// ---------------------------------------------------------------------------

__global__ void k_init(unsigned int* __restrict__ mnb, unsigned int* __restrict__ mxb,
                       int* __restrict__ ccnt) {
    int t = threadIdx.x;
    if (t < BATCH) {
        mnb[t] = 0x7F800000u;   // +inf bits
        mxb[t] = 0u;
        ccnt[t] = 0;
    }
}

// 512 blocks = 32 per image; each covers 8192 contiguous elements.
__global__ void k_hist1(const float* __restrict__ sal, unsigned int* __restrict__ g) {
    __shared__ unsigned int h[4096];
    int t = threadIdx.x;
    int b = blockIdx.x >> 5;
    int start = (blockIdx.x & 31) * 8192;
    const float* p = sal + (size_t)b * HW;
    for (int i = t; i < 4096; i += 256) h[i] = 0u;
    __syncthreads();
    for (int j = 0; j < 32; ++j) {
        unsigned int u = __float_as_uint(p[start + j * 256 + t]);
        atomicAdd(&h[u >> 20], 1u);
    }
    __syncthreads();
    unsigned int* gb = g + b * 4096;
    for (int i = t; i < 4096; i += 256)
        if (h[i]) atomicAdd(&gb[i], h[i]);
}

__global__ void k_hist2(const float* __restrict__ sal,
                        const unsigned int* __restrict__ prefA,
                        const unsigned int* __restrict__ prefB,
                        unsigned int* __restrict__ gA, unsigned int* __restrict__ gB) {
    __shared__ unsigned int hA[4096];
    __shared__ unsigned int hB[4096];
    int t = threadIdx.x;
    int b = blockIdx.x >> 5;
    int start = (blockIdx.x & 31) * 8192;
    const float* p = sal + (size_t)b * HW;
    unsigned int pA = prefA[b], pB = prefB[b];
    for (int i = t; i < 4096; i += 256) { hA[i] = 0u; hB[i] = 0u; }
    __syncthreads();
    for (int j = 0; j < 32; ++j) {
        unsigned int u = __float_as_uint(p[start + j * 256 + t]);
        unsigned int hi = u >> 20, mid = (u >> 8) & 4095u;
        if (hi == pA) atomicAdd(&hA[mid], 1u);
        if (hi == pB) atomicAdd(&hB[mid], 1u);
    }
    __syncthreads();
    unsigned int* ga = gA + b * 4096;
    unsigned int* gb2 = gB + b * 4096;
    for (int i = t; i < 4096; i += 256) {
        if (hA[i]) atomicAdd(&ga[i], hA[i]);
        if (hB[i]) atomicAdd(&gb2[i], hB[i]);
    }
}

__global__ void k_hist3(const float* __restrict__ sal,
                        const unsigned int* __restrict__ prefA,
                        const unsigned int* __restrict__ prefB,
                        unsigned int* __restrict__ gA, unsigned int* __restrict__ gB) {
    __shared__ unsigned int hA[256];
    __shared__ unsigned int hB[256];
    int t = threadIdx.x;
    int b = blockIdx.x >> 5;
    int start = (blockIdx.x & 31) * 8192;
    const float* p = sal + (size_t)b * HW;
    unsigned int pA = prefA[b], pB = prefB[b];
    hA[t] = 0u; hB[t] = 0u;
    __syncthreads();
    for (int j = 0; j < 32; ++j) {
        unsigned int u = __float_as_uint(p[start + j * 256 + t]);
        unsigned int hi = u >> 8, lo = u & 255u;
        if (hi == pA) atomicAdd(&hA[lo], 1u);
        if (hi == pB) atomicAdd(&hB[lo], 1u);
    }
    __syncthreads();
    unsigned int* ga = gA + b * 256;
    unsigned int* gb2 = gB + b * 256;
    if (hA[t]) atomicAdd(&ga[t], hA[t]);
    if (hB[t]) atomicAdd(&gb2[t], hB[t]);
}

// Find bin d (from top) s.t. suffix count crosses krem. Thread-parallel sums,
// thread 0 finishes. Results via shared ints.
__device__ void radix_step(const unsigned int* __restrict__ h, int nbins, int krem,
                           int t, unsigned int* tsum, int* sbin, int* skrem) {
    int bpt = nbins >> 8;
    unsigned int s = 0;
    for (int j = 0; j < bpt; ++j) s += h[t * bpt + j];
    tsum[t] = s;
    __syncthreads();
    if (t == 0) {
        unsigned int cum = 0; int seg = 0;
        for (int d = 255; d >= 0; --d) {
            unsigned int c2 = cum + tsum[d];
            if ((int)c2 >= krem) { seg = d; break; }
            cum = c2;
        }
        unsigned int c = cum;
        for (int j = bpt - 1; j >= 0; --j) {
            unsigned int hv = h[seg * bpt + j];
            if ((int)(c + hv) >= krem) { *sbin = seg * bpt + j; *skrem = krem - (int)c; break; }
            c += hv;
        }
    }
    __syncthreads();
}

__global__ void k_scan1(const unsigned int* __restrict__ g,
                        unsigned int* prefA, int* kremA, unsigned int* prefB, int* kremB) {
    __shared__ unsigned int tsum[256];
    __shared__ int sbin, skrem;
    int b = blockIdx.x, t = threadIdx.x;
    radix_step(g + b * 4096, 4096, KSEL, t, tsum, &sbin, &skrem);
    if (t == 0) { prefA[b] = (unsigned int)sbin; kremA[b] = skrem; }
    __syncthreads();
    radix_step(g + b * 4096, 4096, MCAND, t, tsum, &sbin, &skrem);
    if (t == 0) { prefB[b] = (unsigned int)sbin; kremB[b] = skrem; }
}

__global__ void k_scan2(const unsigned int* __restrict__ gA, const unsigned int* __restrict__ gB,
                        unsigned int* prefA, int* kremA, unsigned int* prefB, int* kremB) {
    __shared__ unsigned int tsum[256];
    __shared__ int sbin, skrem;
    int b = blockIdx.x, t = threadIdx.x;
    radix_step(gA + b * 4096, 4096, kremA[b], t, tsum, &sbin, &skrem);
    if (t == 0) { prefA[b] = (prefA[b] << 12) | (unsigned int)sbin; kremA[b] = skrem; }
    __syncthreads();
    radix_step(gB + b * 4096, 4096, kremB[b], t, tsum, &sbin, &skrem);
    if (t == 0) { prefB[b] = (prefB[b] << 12) | (unsigned int)sbin; kremB[b] = skrem; }
}

__global__ void k_scan3(const unsigned int* __restrict__ gA, const unsigned int* __restrict__ gB,
                        const unsigned int* prefA, const int* kremA,
                        const unsigned int* prefB, const int* kremB,
                        unsigned int* __restrict__ ucut) {
    __shared__ unsigned int tsum[256];
    __shared__ int sbin, skrem;
    __shared__ unsigned int thrbits;
    int b = blockIdx.x, t = threadIdx.x;
    radix_step(gA + b * 256, 256, kremA[b], t, tsum, &sbin, &skrem);
    if (t == 0) {
        unsigned int kth = (prefA[b] << 8) | (unsigned int)sbin;
        float thr = fmaxf(__uint_as_float(kth), 0.1f);
        thrbits = __float_as_uint(thr);
    }
    __syncthreads();
    radix_step(gB + b * 256, 256, kremB[b], t, tsum, &sbin, &skrem);
    if (t == 0) {
        unsigned int c80 = (prefB[b] << 8) | (unsigned int)sbin;
        ucut[b] = (c80 > thrbits) ? c80 : thrbits;   // uint order == float order (>=0)
    }
}

__global__ void k_collect(const float* __restrict__ sal, const unsigned int* __restrict__ ucut,
                          float* __restrict__ candv, int* __restrict__ candi,
                          int* __restrict__ ccnt) {
    int t = threadIdx.x;
    int b = blockIdx.x >> 5;
    int start = (blockIdx.x & 31) * 8192;
    const float* p = sal + (size_t)b * HW;
    unsigned int cut = ucut[b];
    for (int j = 0; j < 32; ++j) {
        int i = start + j * 256 + t;
        unsigned int u = __float_as_uint(p[i]);
        if (u >= cut) {
            int pos = atomicAdd(&ccnt[b], 1);
            if (pos < CAP) { candv[b * CAP + pos] = p[i]; candi[b * CAP + pos] = i; }
        }
    }
}

// Rank (value desc, index asc — lax.top_k tie rule), greedy NMS, write output.
__global__ void k_final(const float* __restrict__ candv, const int* __restrict__ candi,
                        const int* __restrict__ ccnt, float* __restrict__ out) {
    __shared__ float cval[CAP];
    __shared__ int   cidx[CAP];
    __shared__ float sv[MCAND];
    __shared__ int   si[MCAND];
    int b = blockIdx.x, t = threadIdx.x;
    int n = min(ccnt[b], CAP);
    for (int i = t; i < n; i += 256) { cval[i] = candv[b * CAP + i]; cidx[i] = candi[b * CAP + i]; }
    __syncthreads();
    int m = min(n, MCAND);
    for (int i = t; i < n; i += 256) {
        float vi = cval[i]; int ii = cidx[i];
        int rank = 0;
        for (int j = 0; j < n; j++) {
            float vj = cval[j];
            if (vj > vi || (vj == vi && cidx[j] < ii)) rank++;
        }
        if (rank < MCAND) { sv[rank] = vi; si[rank] = ii; }
    }
    __syncthreads();
    if (t == 0) {
        float kx[TOPK], ky[TOPK];
        int cnt = 0;
        for (int i = 0; i < m; i++) {
            float x = (float)(si[i] & 511);
            float y = (float)(si[i] >> 9);
            bool near_kept = false;
            for (int j = 0; j < cnt; j++) {
                float dx = kx[j] - x, dy = ky[j] - y;
                if (dx * dx + dy * dy < 100.0f) near_kept = true;
            }
            if (!near_kept && cnt < TOPK) { kx[cnt] = x; ky[cnt] = y; cnt++; }
        }
        for (int j = 0; j < TOPK; j++) {
            out[b * 10 + 2 * j]     = (j < cnt) ? kx[j] : -1.0f;
            out[b * 10 + 2 * j + 1] = (j < cnt) ? ky[j] : -1.0f;
            out[160 + b * 5 + j]    = (j < cnt) ? 1.0f : -1.0f;
        }
    }
}

extern "C" void kernel_launch(void* const* d_in, const int* in_sizes, int n_in,
                              void* d_out, int out_size, void* d_ws, size_t ws_size,
                              hipStream_t stream) {
    const float* img = (const float*)d_in[0];
    float* out = (float*)d_out;
    char* ws = (char*)d_ws;

    // ws layout (bytes):
    //   [0, 32M)    : A (complex)  -> later hblur tmp (16.8M) -> later hist/cand region
    //   [32M, 48M)  : Bc lo half / salraw
    //   [32M, 64M)  : Bc (complex)
    //   [48M, 64M)  : salb
    //   [64M, +512) : stats
    float2* A      = (float2*)ws;
    float2* Bc     = (float2*)(ws + 33554432UL);
    float*  salraw = (float*)(ws + 33554432UL);
    float*  tmp    = (float*)ws;
    float*  salb   = (float*)(ws + 50331648UL);

    // hist/cand region overlays A/tmp (dead after vblur); memset AFTER vblur.
    unsigned int* hist1  = (unsigned int*)(ws + 0UL);        // 16*4096 u32 = 256KB
    unsigned int* hist2a = (unsigned int*)(ws + 262144UL);   // 256KB
    unsigned int* hist2b = (unsigned int*)(ws + 524288UL);   // 256KB
    unsigned int* hist3a = (unsigned int*)(ws + 786432UL);   // 16KB
    unsigned int* hist3b = (unsigned int*)(ws + 802816UL);   // 16KB
    float*        candv  = (float*)(ws + 819200UL);          // 16*2048 f32 = 128KB
    int*          candi  = (int*)(ws + 950272UL);            // 128KB
    const size_t HISTBYTES = 819200UL;                       // hists only

    unsigned int* stats = (unsigned int*)(ws + 67108864UL);
    unsigned int* prefA = stats + 0;
    int*          kremA = (int*)(stats + 16);
    unsigned int* prefB = stats + 32;
    int*          kremB = (int*)(stats + 48);
    unsigned int* ucut  = stats + 64;
    unsigned int* mnb   = stats + 80;
    unsigned int* mxb   = stats + 96;
    int*          ccnt  = (int*)(stats + 112);

    float* salout = out + 240;   // sal region of d_out

    k_init<<<dim3(1), dim3(64), 0, stream>>>(mnb, mxb, ccnt);
    k_win_rowfft<<<dim3(8192), dim3(256), 0, stream>>>(img, A);
    k_transpose<<<dim3(16, 16, 16), dim3(32, 8), 0, stream>>>(A, Bc);
    k_phase<<<dim3(8192), dim3(256), 0, stream>>>(Bc);                 // fwd-H + phase + inv-H
    k_transpose<<<dim3(16, 16, 16), dim3(32, 8), 0, stream>>>(Bc, A);
    k_rowfft_mag<<<dim3(8192), dim3(256), 0, stream>>>(A, salraw);     // inv-W + scale + |.|^2
    k_hblur<<<dim3(16384), dim3(256), 0, stream>>>(salraw, tmp);
    k_vblur<<<dim3(16384), dim3(256), 0, stream>>>(tmp, salb, mnb, mxb);
    hipMemsetAsync(ws, 0, HISTBYTES, stream);                          // zero hists (tmp now dead)
    k_norm<<<dim3(16384), dim3(256), 0, stream>>>(salb, mnb, mxb, salout);
    k_hist1<<<dim3(512), dim3(256), 0, stream>>>(salout, hist1);
    k_scan1<<<dim3(BATCH), dim3(256), 0, stream>>>(hist1, prefA, kremA, prefB, kremB);
    k_hist2<<<dim3(512), dim3(256), 0, stream>>>(salout, prefA, prefB, hist2a, hist2b);
    k_scan2<<<dim3(BATCH), dim3(256), 0, stream>>>(hist2a, hist2b, prefA, kremA, prefB, kremB);
    k_hist3<<<dim3(512), dim3(256), 0, stream>>>(salout, prefA, prefB, hist3a, hist3b);
    k_scan3<<<dim3(BATCH), dim3(256), 0, stream>>>(hist3a, hist3b, prefA, kremA, prefB, kremB, ucut);
    k_collect<<<dim3(512), dim3(256), 0, stream>>>(salout, ucut, candv, candi, ccnt);
    k_final<<<dim3(BATCH), dim3(256), 0, stream>>>(candv, candi, ccnt, out);
}

// Round 3
// 285.343 us; speedup vs baseline: 7.3264x; 1.7975x over previous
//
#include <hip/hip_runtime.h>
#include <math.h>

#define BATCH 16
#define HW 262144          // 512*512
#define KSEL 26214         // int(0.1 * 262144)
#define MCAND 80           // TOP_K * CAND_MULT
#define TOPK 5
#define CAP 2048

// ---------------------------------------------------------------------------
// FFT: in-LDS Stockham radix-2, N=512, 256 threads (1 butterfly/thread/stage).
// dir = -1 forward, +1 inverse (unnormalized). Caller syncs after filling s0.
// Twiddles via HW v_sin/v_cos (input in revolutions, |rev| < 0.5 -> in range).
// ---------------------------------------------------------------------------
__device__ float2* fft512(float2* s0, float2* s1, int t, float dir) {
    float2* src = s0;
    float2* dst = s1;
    #pragma unroll
    for (int Ns = 1; Ns < 512; Ns <<= 1) {
        float2 a = src[t];
        float2 b = src[t + 256];
        int r = t & (Ns - 1);
        float rev = dir * ((float)r * (0.5f / (float)Ns));   // angle / 2pi
        float sn = __builtin_amdgcn_sinf(rev);
        float cs = __builtin_amdgcn_cosf(rev);
        float2 wb = make_float2(cs * b.x - sn * b.y, cs * b.y + sn * b.x);
        int d = ((t - r) << 1) + r;
        dst[d]      = make_float2(a.x + wb.x, a.y + wb.y);
        dst[d + Ns] = make_float2(a.x - wb.x, a.y - wb.y);
        float2* tm = src; src = dst; dst = tm;
        __syncthreads();
    }
    return src;
}

// K1: window + forward FFT along W. One block per (b, h) row.
__global__ void k_win_rowfft(const float* __restrict__ img, float2* __restrict__ A) {
    __shared__ float2 s0[512];
    __shared__ float2 s1[512];
    int row = blockIdx.x;           // b*512 + h
    int h = row & 511;
    int t = threadIdx.x;
    float wr = 0.5f * (1.0f - __builtin_amdgcn_cosf((float)h * (1.0f / 511.0f)));
    const float* p = img + (size_t)row * 512;
    for (int i = t; i < 512; i += 256) {
        float wc = 0.5f * (1.0f - __builtin_amdgcn_cosf((float)i * (1.0f / 511.0f)));
        s0[i] = make_float2(p[i] * wr * wc, 0.0f);
    }
    __syncthreads();
    float2* res = fft512(s0, s1, t, -1.0f);
    float2* out = A + (size_t)row * 512;
    for (int i = t; i < 512; i += 256) out[i] = res[i];
}

// Fused: forward FFT along H (completing the 2D FFT) -> phase-only normalize
// -> inverse FFT along H. Data is transposed, so "rows" here are H-columns.
__global__ void k_phase(float2* __restrict__ X) {
    __shared__ float2 s0[512];
    __shared__ float2 s1[512];
    int row = blockIdx.x;
    int t = threadIdx.x;
    float2* p = X + (size_t)row * 512;
    for (int i = t; i < 512; i += 256) s0[i] = p[i];
    __syncthreads();
    float2* res = fft512(s0, s1, t, -1.0f);
    for (int i = t; i < 512; i += 256) {
        float2 v = res[i];
        float m = sqrtf(v.x * v.x + v.y * v.y);
        if (m > 0.0f) { v.x /= m; v.y /= m; }
        else          { v = make_float2(1.0f, 0.0f); }
        res[i] = v;
    }
    __syncthreads();
    float2* other = (res == s0) ? s1 : s0;
    float2* res2 = fft512(res, other, t, 1.0f);
    for (int i = t; i < 512; i += 256) p[i] = res2[i];
}

// Gaussian blur coefficients, sigma=1, 5-tap.
#define GW0 0.05448868454964294f
#define GW1 0.24420134200323332f
#define GW2 0.40261994689424746f

// Final inverse row FFT + 1/(H*W) scaling + |.|^2 + horizontal 5-tap blur.
__global__ void k_mag_hblur(const float2* __restrict__ X, float* __restrict__ out) {
    __shared__ float2 s0[512];
    __shared__ float2 s1[512];
    __shared__ float smag[512];
    int row = blockIdx.x;
    int t = threadIdx.x;
    const float2* p = X + (size_t)row * 512;
    for (int i = t; i < 512; i += 256) s0[i] = p[i];
    __syncthreads();
    float2* res = fft512(s0, s1, t, 1.0f);
    const float s = 3.814697265625e-06f;   // 1/262144, exact
    for (int i = t; i < 512; i += 256) {
        float re = res[i].x * s, im = res[i].y * s;
        smag[i] = re * re + im * im;
    }
    __syncthreads();
    float* o = out + (size_t)row * 512;
    for (int i = t; i < 512; i += 256) {
        float acc = GW2 * smag[i];
        if (i >= 1)   acc += GW1 * smag[i - 1];
        if (i >= 2)   acc += GW0 * smag[i - 2];
        if (i <= 510) acc += GW1 * smag[i + 1];
        if (i <= 509) acc += GW0 * smag[i + 2];
        o[i] = acc;
    }
}

// Per-image 512x512 complex transpose, 32x32 tiles.
__global__ void k_transpose(const float2* __restrict__ in, float2* __restrict__ out) {
    __shared__ float2 tile[32][33];
    int b = blockIdx.z;
    int x0 = blockIdx.x * 32, y0 = blockIdx.y * 32;
    const float2* ib = in + (size_t)b * HW;
    float2* ob = out + (size_t)b * HW;
    int tx = threadIdx.x, ty = threadIdx.y;
    #pragma unroll
    for (int i = 0; i < 32; i += 8)
        tile[ty + i][tx] = ib[(size_t)(y0 + ty + i) * 512 + x0 + tx];
    __syncthreads();
    #pragma unroll
    for (int i = 0; i < 32; i += 8)
        ob[(size_t)(x0 + ty + i) * 512 + y0 + tx] = tile[tx][ty + i];
}

// Vertical blur + per-BLOCK min/max partials (no atomics).
__global__ void k_vblur(const float* __restrict__ in, float* __restrict__ out,
                        float* __restrict__ pmn, float* __restrict__ pmx) {
    __shared__ float smn[256];
    __shared__ float smx[256];
    int t = threadIdx.x;
    int i = blockIdx.x * 256 + t;
    int y = (i >> 9) & 511;
    float acc = GW2 * in[i];
    if (y >= 1)   acc += GW1 * in[i - 512];
    if (y >= 2)   acc += GW0 * in[i - 1024];
    if (y <= 510) acc += GW1 * in[i + 512];
    if (y <= 509) acc += GW0 * in[i + 1024];
    out[i] = acc;
    smn[t] = acc; smx[t] = acc;
    __syncthreads();
    for (int s = 128; s > 0; s >>= 1) {
        if (t < s) { smn[t] = fminf(smn[t], smn[t + s]); smx[t] = fmaxf(smx[t], smx[t + s]); }
        __syncthreads();
    }
    if (t == 0) { pmn[blockIdx.x] = smn[0]; pmx[blockIdx.x] = smx[0]; }
}

// Fold 1024 partials per image -> mnf/mxf.
__global__ void k_reduce(const float* __restrict__ pmn, const float* __restrict__ pmx,
                         float* __restrict__ mnf, float* __restrict__ mxf) {
    __shared__ float smn[256];
    __shared__ float smx[256];
    int b = blockIdx.x, t = threadIdx.x;
    float lmn = INFINITY, lmx = -INFINITY;
    for (int j = t; j < 1024; j += 256) {
        lmn = fminf(lmn, pmn[b * 1024 + j]);
        lmx = fmaxf(lmx, pmx[b * 1024 + j]);
    }
    smn[t] = lmn; smx[t] = lmx;
    __syncthreads();
    for (int s = 128; s > 0; s >>= 1) {
        if (t < s) { smn[t] = fminf(smn[t], smn[t + s]); smx[t] = fmaxf(smx[t], smx[t + s]); }
        __syncthreads();
    }
    if (t == 0) { mnf[b] = smn[0]; mxf[b] = smx[0]; }
}

// Normalize + border mask -> final saliency (d_out), fused with hist round 1.
__global__ void k_norm_hist(const float* __restrict__ in, const float* __restrict__ mnf,
                            const float* __restrict__ mxf, float* __restrict__ out,
                            unsigned int* __restrict__ g) {
    __shared__ unsigned int h[4096];
    int t = threadIdx.x;
    int b = blockIdx.x >> 5;
    int base = b * HW + (blockIdx.x & 31) * 8192;
    float mn = mnf[b], mx = mxf[b];
    float inv = 1.0f / (mx - mn + 1e-8f);
    for (int i = t; i < 4096; i += 256) h[i] = 0u;
    __syncthreads();
    for (int j = 0; j < 32; ++j) {
        int idx = base + j * 256 + t;
        float v = (in[idx] - mn) * inv;
        int xx = idx & 511, yy = (idx >> 9) & 511;
        bool inside = (xx >= 12) && (xx < 500) && (yy >= 12) && (yy < 500);
        v = inside ? v : 0.0f;
        out[idx] = v;
        atomicAdd(&h[__float_as_uint(v) >> 20], 1u);
    }
    __syncthreads();
    unsigned int* gb = g + b * 4096;
    for (int i = t; i < 4096; i += 256)
        if (h[i]) atomicAdd(&gb[i], h[i]);
}

// ---------------------------------------------------------------------------
// Parallel 3-round radix select (bits 12/12/8) for BOTH k=26214 (threshold)
// and k=80 (candidate cutoff), sharing the same histogram passes.
// ---------------------------------------------------------------------------

__global__ void k_hist2(const float* __restrict__ sal,
                        const unsigned int* __restrict__ prefA,
                        const unsigned int* __restrict__ prefB,
                        unsigned int* __restrict__ gA, unsigned int* __restrict__ gB) {
    __shared__ unsigned int hA[4096];
    __shared__ unsigned int hB[4096];
    int t = threadIdx.x;
    int b = blockIdx.x >> 5;
    int start = (blockIdx.x & 31) * 8192;
    const float* p = sal + (size_t)b * HW;
    unsigned int pA = prefA[b], pB = prefB[b];
    for (int i = t; i < 4096; i += 256) { hA[i] = 0u; hB[i] = 0u; }
    __syncthreads();
    for (int j = 0; j < 32; ++j) {
        unsigned int u = __float_as_uint(p[start + j * 256 + t]);
        unsigned int hi = u >> 20, mid = (u >> 8) & 4095u;
        if (hi == pA) atomicAdd(&hA[mid], 1u);
        if (hi == pB) atomicAdd(&hB[mid], 1u);
    }
    __syncthreads();
    unsigned int* ga = gA + b * 4096;
    unsigned int* gb2 = gB + b * 4096;
    for (int i = t; i < 4096; i += 256) {
        if (hA[i]) atomicAdd(&ga[i], hA[i]);
        if (hB[i]) atomicAdd(&gb2[i], hB[i]);
    }
}

__global__ void k_hist3(const float* __restrict__ sal,
                        const unsigned int* __restrict__ prefA,
                        const unsigned int* __restrict__ prefB,
                        unsigned int* __restrict__ gA, unsigned int* __restrict__ gB) {
    __shared__ unsigned int hA[256];
    __shared__ unsigned int hB[256];
    int t = threadIdx.x;
    int b = blockIdx.x >> 5;
    int start = (blockIdx.x & 31) * 8192;
    const float* p = sal + (size_t)b * HW;
    unsigned int pA = prefA[b], pB = prefB[b];
    hA[t] = 0u; hB[t] = 0u;
    __syncthreads();
    for (int j = 0; j < 32; ++j) {
        unsigned int u = __float_as_uint(p[start + j * 256 + t]);
        unsigned int hi = u >> 8, lo = u & 255u;
        if (hi == pA) atomicAdd(&hA[lo], 1u);
        if (hi == pB) atomicAdd(&hB[lo], 1u);
    }
    __syncthreads();
    unsigned int* ga = gA + b * 256;
    unsigned int* gb2 = gB + b * 256;
    if (hA[t]) atomicAdd(&ga[t], hA[t]);
    if (hB[t]) atomicAdd(&gb2[t], hB[t]);
}

// Find bin d (from top) s.t. suffix count crosses krem.
__device__ void radix_step(const unsigned int* __restrict__ h, int nbins, int krem,
                           int t, unsigned int* tsum, int* sbin, int* skrem) {
    int bpt = nbins >> 8;
    unsigned int s = 0;
    for (int j = 0; j < bpt; ++j) s += h[t * bpt + j];
    tsum[t] = s;
    __syncthreads();
    if (t == 0) {
        unsigned int cum = 0; int seg = 0;
        for (int d = 255; d >= 0; --d) {
            unsigned int c2 = cum + tsum[d];
            if ((int)c2 >= krem) { seg = d; break; }
            cum = c2;
        }
        unsigned int c = cum;
        for (int j = bpt - 1; j >= 0; --j) {
            unsigned int hv = h[seg * bpt + j];
            if ((int)(c + hv) >= krem) { *sbin = seg * bpt + j; *skrem = krem - (int)c; break; }
            c += hv;
        }
    }
    __syncthreads();
}

__global__ void k_scan1(const unsigned int* __restrict__ g,
                        unsigned int* prefA, int* kremA, unsigned int* prefB, int* kremB) {
    __shared__ unsigned int tsum[256];
    __shared__ int sbin, skrem;
    int b = blockIdx.x, t = threadIdx.x;
    radix_step(g + b * 4096, 4096, KSEL, t, tsum, &sbin, &skrem);
    if (t == 0) { prefA[b] = (unsigned int)sbin; kremA[b] = skrem; }
    __syncthreads();
    radix_step(g + b * 4096, 4096, MCAND, t, tsum, &sbin, &skrem);
    if (t == 0) { prefB[b] = (unsigned int)sbin; kremB[b] = skrem; }
}

__global__ void k_scan2(const unsigned int* __restrict__ gA, const unsigned int* __restrict__ gB,
                        unsigned int* prefA, int* kremA, unsigned int* prefB, int* kremB) {
    __shared__ unsigned int tsum[256];
    __shared__ int sbin, skrem;
    int b = blockIdx.x, t = threadIdx.x;
    radix_step(gA + b * 4096, 4096, kremA[b], t, tsum, &sbin, &skrem);
    if (t == 0) { prefA[b] = (prefA[b] << 12) | (unsigned int)sbin; kremA[b] = skrem; }
    __syncthreads();
    radix_step(gB + b * 4096, 4096, kremB[b], t, tsum, &sbin, &skrem);
    if (t == 0) { prefB[b] = (prefB[b] << 12) | (unsigned int)sbin; kremB[b] = skrem; }
}

__global__ void k_scan3(const unsigned int* __restrict__ gA, const unsigned int* __restrict__ gB,
                        const unsigned int* prefA, const int* kremA,
                        const unsigned int* prefB, const int* kremB,
                        unsigned int* __restrict__ ucut) {
    __shared__ unsigned int tsum[256];
    __shared__ int sbin, skrem;
    __shared__ unsigned int thrbits;
    int b = blockIdx.x, t = threadIdx.x;
    radix_step(gA + b * 256, 256, kremA[b], t, tsum, &sbin, &skrem);
    if (t == 0) {
        unsigned int kth = (prefA[b] << 8) | (unsigned int)sbin;
        float thr = fmaxf(__uint_as_float(kth), 0.1f);
        thrbits = __float_as_uint(thr);
    }
    __syncthreads();
    radix_step(gB + b * 256, 256, kremB[b], t, tsum, &sbin, &skrem);
    if (t == 0) {
        unsigned int c80 = (prefB[b] << 8) | (unsigned int)sbin;
        ucut[b] = (c80 > thrbits) ? c80 : thrbits;   // uint order == float order (>=0)
    }
}

__global__ void k_collect(const float* __restrict__ sal, const unsigned int* __restrict__ ucut,
                          float* __restrict__ candv, int* __restrict__ candi,
                          int* __restrict__ ccnt) {
    int t = threadIdx.x;
    int b = blockIdx.x >> 5;
    int start = (blockIdx.x & 31) * 8192;
    const float* p = sal + (size_t)b * HW;
    unsigned int cut = ucut[b];
    for (int j = 0; j < 32; ++j) {
        int i = start + j * 256 + t;
        unsigned int u = __float_as_uint(p[i]);
        if (u >= cut) {
            int pos = atomicAdd(&ccnt[b], 1);
            if (pos < CAP) { candv[b * CAP + pos] = p[i]; candi[b * CAP + pos] = i; }
        }
    }
}

// Rank (value desc, index asc — lax.top_k tie rule), greedy NMS, write output.
__global__ void k_final(const float* __restrict__ candv, const int* __restrict__ candi,
                        const int* __restrict__ ccnt, float* __restrict__ out) {
    __shared__ float cval[CAP];
    __shared__ int   cidx[CAP];
    __shared__ float sv[MCAND];
    __shared__ int   si[MCAND];
    int b = blockIdx.x, t = threadIdx.x;
    int n = min(ccnt[b], CAP);
    for (int i = t; i < n; i += 256) { cval[i] = candv[b * CAP + i]; cidx[i] = candi[b * CAP + i]; }
    __syncthreads();
    int m = min(n, MCAND);
    for (int i = t; i < n; i += 256) {
        float vi = cval[i]; int ii = cidx[i];
        int rank = 0;
        for (int j = 0; j < n; j++) {
            float vj = cval[j];
            if (vj > vi || (vj == vi && cidx[j] < ii)) rank++;
        }
        if (rank < MCAND) { sv[rank] = vi; si[rank] = ii; }
    }
    __syncthreads();
    if (t == 0) {
        float kx[TOPK], ky[TOPK];
        int cnt = 0;
        for (int i = 0; i < m; i++) {
            float x = (float)(si[i] & 511);
            float y = (float)(si[i] >> 9);
            bool near_kept = false;
            for (int j = 0; j < cnt; j++) {
                float dx = kx[j] - x, dy = ky[j] - y;
                if (dx * dx + dy * dy < 100.0f) near_kept = true;
            }
            if (!near_kept && cnt < TOPK) { kx[cnt] = x; ky[cnt] = y; cnt++; }
        }
        for (int j = 0; j < TOPK; j++) {
            out[b * 10 + 2 * j]     = (j < cnt) ? kx[j] : -1.0f;
            out[b * 10 + 2 * j + 1] = (j < cnt) ? ky[j] : -1.0f;
            out[160 + b * 5 + j]    = (j < cnt) ? 1.0f : -1.0f;
        }
    }
}

extern "C" void kernel_launch(void* const* d_in, const int* in_sizes, int n_in,
                              void* d_out, int out_size, void* d_ws, size_t ws_size,
                              hipStream_t stream) {
    const float* img = (const float*)d_in[0];
    float* out = (float*)d_out;
    char* ws = (char*)d_ws;

    // ws layout (bytes):
    //   [0, 32M)   : A (complex). Dead after k_mag_hblur. Then reused:
    //                  [0, ~1.1M) hists + ccnt + cand   (memset after vblur)
    //                  [20M, 20M+128K) pmn/pmx partials (written by vblur)
    //   [32M, 64M) : Bc (complex). Dead after transpose #2. Then:
    //                  [32M, 48M) hb (h-blurred saliency)
    //   [48M, 64M) : salb (v-blurred)
    //   [64M, +448): scalar stats
    float2* A   = (float2*)ws;
    float2* Bc  = (float2*)(ws + 33554432UL);
    float*  hb  = (float*)(ws + 33554432UL);
    float*  salb = (float*)(ws + 50331648UL);

    unsigned int* hist1  = (unsigned int*)(ws + 0UL);        // 16*4096 u32 = 256KB
    unsigned int* hist2a = (unsigned int*)(ws + 262144UL);   // 256KB
    unsigned int* hist2b = (unsigned int*)(ws + 524288UL);   // 256KB
    unsigned int* hist3a = (unsigned int*)(ws + 786432UL);   // 16KB
    unsigned int* hist3b = (unsigned int*)(ws + 802816UL);   // 16KB
    int*          ccnt   = (int*)(ws + 819200UL);            // 64B
    const size_t  ZEROBYTES = 819264UL;
    float*        candv  = (float*)(ws + 851968UL);          // 128KB
    int*          candi  = (int*)(ws + 983040UL);            // 128KB

    float* pmn = (float*)(ws + 20971520UL);                  // 64KB (16384 f32)
    float* pmx = (float*)(ws + 21037056UL);                  // 64KB

    char* stats = ws + 67108864UL;
    unsigned int* prefA = (unsigned int*)(stats + 0);
    int*          kremA = (int*)(stats + 64);
    unsigned int* prefB = (unsigned int*)(stats + 128);
    int*          kremB = (int*)(stats + 192);
    unsigned int* ucut  = (unsigned int*)(stats + 256);
    float*        mnf   = (float*)(stats + 320);
    float*        mxf   = (float*)(stats + 384);

    float* salout = out + 240;   // sal region of d_out

    k_win_rowfft<<<dim3(8192), dim3(256), 0, stream>>>(img, A);
    k_transpose<<<dim3(16, 16, 16), dim3(32, 8), 0, stream>>>(A, Bc);
    k_phase<<<dim3(8192), dim3(256), 0, stream>>>(Bc);                 // fwd-H + phase + inv-H
    k_transpose<<<dim3(16, 16, 16), dim3(32, 8), 0, stream>>>(Bc, A);
    k_mag_hblur<<<dim3(8192), dim3(256), 0, stream>>>(A, hb);          // inv-W + |.|^2 + hblur
    k_vblur<<<dim3(16384), dim3(256), 0, stream>>>(hb, salb, pmn, pmx);
    hipMemsetAsync(ws, 0, ZEROBYTES, stream);                          // hists + ccnt (A dead)
    k_reduce<<<dim3(BATCH), dim3(256), 0, stream>>>(pmn, pmx, mnf, mxf);
    k_norm_hist<<<dim3(512), dim3(256), 0, stream>>>(salb, mnf, mxf, salout, hist1);
    k_scan1<<<dim3(BATCH), dim3(256), 0, stream>>>(hist1, prefA, kremA, prefB, kremB);
    k_hist2<<<dim3(512), dim3(256), 0, stream>>>(salout, prefA, prefB, hist2a, hist2b);
    k_scan2<<<dim3(BATCH), dim3(256), 0, stream>>>(hist2a, hist2b, prefA, kremA, prefB, kremB);
    k_hist3<<<dim3(512), dim3(256), 0, stream>>>(salout, prefA, prefB, hist3a, hist3b);
    k_scan3<<<dim3(BATCH), dim3(256), 0, stream>>>(hist3a, hist3b, prefA, kremA, prefB, kremB, ucut);
    k_collect<<<dim3(512), dim3(256), 0, stream>>>(salout, ucut, candv, candi, ccnt);
    k_final<<<dim3(BATCH), dim3(256), 0, stream>>>(candv, candi, ccnt, out);
}

// Round 4
// 250.675 us; speedup vs baseline: 8.3396x; 1.1383x over previous
//
#include <hip/hip_runtime.h>
#include <math.h>

#define BATCH 16
#define HW 262144          // 512*512
#define KSEL 26214         // int(0.1 * 262144)
#define MCAND 80           // TOP_K * CAND_MULT
#define TOPK 5
#define CAP 2048

// ---------------------------------------------------------------------------
// FFT: in-LDS Stockham radix-2, N=512, 256 threads, SoA re/im (bank-conflict
// free: b32 accesses, stride patterns <= 2-way which is free on CDNA4).
// dir = -1 forward, +1 inverse (unnormalized). Caller syncs after filling r0/i0.
// Twiddles via HW v_sin/v_cos (input in revolutions, |rev| <= 0.5 in range).
// ---------------------------------------------------------------------------
struct FP { float* r; float* i; };

__device__ FP fft512(float* r0, float* i0, float* r1, float* i1, int t, float dir) {
    float *sr = r0, *si = i0, *dr = r1, *di = i1;
    #pragma unroll
    for (int Ns = 1; Ns < 512; Ns <<= 1) {
        float ax = sr[t],       ay = si[t];
        float bx = sr[t + 256], by = si[t + 256];
        int r = t & (Ns - 1);
        float rev = dir * ((float)r * (0.5f / (float)Ns));   // angle / 2pi
        float sn = __builtin_amdgcn_sinf(rev);
        float cs = __builtin_amdgcn_cosf(rev);
        float wx = cs * bx - sn * by;
        float wy = cs * by + sn * bx;
        int d = ((t - r) << 1) + r;
        dr[d]      = ax + wx;  di[d]      = ay + wy;
        dr[d + Ns] = ax - wx;  di[d + Ns] = ay - wy;
        float* tp;
        tp = sr; sr = dr; dr = tp;
        tp = si; si = di; di = tp;
        __syncthreads();
    }
    FP p; p.r = sr; p.i = si; return p;
}

// K1: window + forward FFT along W. One block per (b, h) row.
__global__ void k_win_rowfft(const float* __restrict__ img, float2* __restrict__ A) {
    __shared__ float r0[512], i0[512], r1[512], i1[512];
    int row = blockIdx.x;           // b*512 + h
    int h = row & 511;
    int t = threadIdx.x;
    float wr = 0.5f * (1.0f - __builtin_amdgcn_cosf((float)h * (1.0f / 511.0f)));
    const float* p = img + (size_t)row * 512;
    for (int i = t; i < 512; i += 256) {
        float wc = 0.5f * (1.0f - __builtin_amdgcn_cosf((float)i * (1.0f / 511.0f)));
        r0[i] = p[i] * wr * wc;
        i0[i] = 0.0f;
    }
    __syncthreads();
    FP res = fft512(r0, i0, r1, i1, t, -1.0f);
    float2* out = A + (size_t)row * 512;
    for (int i = t; i < 512; i += 256) out[i] = make_float2(res.r[i], res.i[i]);
}

// Fused: forward FFT along H (completing the 2D FFT) -> phase-only normalize
// -> inverse FFT along H. Data is transposed, so "rows" here are H-columns.
__global__ void k_phase(float2* __restrict__ X) {
    __shared__ float r0[512], i0[512], r1[512], i1[512];
    int row = blockIdx.x;
    int t = threadIdx.x;
    float2* p = X + (size_t)row * 512;
    for (int i = t; i < 512; i += 256) {
        float2 v = p[i];
        r0[i] = v.x; i0[i] = v.y;
    }
    __syncthreads();
    FP res = fft512(r0, i0, r1, i1, t, -1.0f);
    for (int i = t; i < 512; i += 256) {
        float x = res.r[i], y = res.i[i];
        float m2 = x * x + y * y;
        if (m2 > 0.0f) {
            float inv = rsqrtf(m2);
            res.r[i] = x * inv; res.i[i] = y * inv;
        } else {
            res.r[i] = 1.0f; res.i[i] = 0.0f;
        }
    }
    __syncthreads();
    float* orr = (res.r == r0) ? r1 : r0;
    float* oii = (res.i == i0) ? i1 : i0;
    FP res2 = fft512(res.r, res.i, orr, oii, t, 1.0f);
    for (int i = t; i < 512; i += 256) p[i] = make_float2(res2.r[i], res2.i[i]);
}

// Gaussian blur coefficients, sigma=1, 5-tap.
#define GW0 0.05448868454964294f
#define GW1 0.24420134200323332f
#define GW2 0.40261994689424746f

// Final inverse row FFT + 1/(H*W) scaling + |.|^2 + horizontal 5-tap blur.
__global__ void k_mag_hblur(const float2* __restrict__ X, float* __restrict__ out) {
    __shared__ float r0[512], i0[512], r1[512], i1[512];
    __shared__ float smag[512];
    int row = blockIdx.x;
    int t = threadIdx.x;
    const float2* p = X + (size_t)row * 512;
    for (int i = t; i < 512; i += 256) {
        float2 v = p[i];
        r0[i] = v.x; i0[i] = v.y;
    }
    __syncthreads();
    FP res = fft512(r0, i0, r1, i1, t, 1.0f);
    const float s = 3.814697265625e-06f;   // 1/262144, exact
    for (int i = t; i < 512; i += 256) {
        float re = res.r[i] * s, im = res.i[i] * s;
        smag[i] = re * re + im * im;
    }
    __syncthreads();
    float* o = out + (size_t)row * 512;
    for (int i = t; i < 512; i += 256) {
        float acc = GW2 * smag[i];
        if (i >= 1)   acc += GW1 * smag[i - 1];
        if (i >= 2)   acc += GW0 * smag[i - 2];
        if (i <= 510) acc += GW1 * smag[i + 1];
        if (i <= 509) acc += GW0 * smag[i + 2];
        o[i] = acc;
    }
}

// Per-image 512x512 complex transpose, 32x32 tiles.
__global__ void k_transpose(const float2* __restrict__ in, float2* __restrict__ out) {
    __shared__ float2 tile[32][33];
    int b = blockIdx.z;
    int x0 = blockIdx.x * 32, y0 = blockIdx.y * 32;
    const float2* ib = in + (size_t)b * HW;
    float2* ob = out + (size_t)b * HW;
    int tx = threadIdx.x, ty = threadIdx.y;
    #pragma unroll
    for (int i = 0; i < 32; i += 8)
        tile[ty + i][tx] = ib[(size_t)(y0 + ty + i) * 512 + x0 + tx];
    __syncthreads();
    #pragma unroll
    for (int i = 0; i < 32; i += 8)
        ob[(size_t)(x0 + ty + i) * 512 + y0 + tx] = tile[tx][ty + i];
}

// Vertical blur + per-BLOCK min/max partials (no atomics).
__global__ void k_vblur(const float* __restrict__ in, float* __restrict__ out,
                        float* __restrict__ pmn, float* __restrict__ pmx) {
    __shared__ float smn[256];
    __shared__ float smx[256];
    int t = threadIdx.x;
    int i = blockIdx.x * 256 + t;
    int y = (i >> 9) & 511;
    float acc = GW2 * in[i];
    if (y >= 1)   acc += GW1 * in[i - 512];
    if (y >= 2)   acc += GW0 * in[i - 1024];
    if (y <= 510) acc += GW1 * in[i + 512];
    if (y <= 509) acc += GW0 * in[i + 1024];
    out[i] = acc;
    smn[t] = acc; smx[t] = acc;
    __syncthreads();
    for (int s = 128; s > 0; s >>= 1) {
        if (t < s) { smn[t] = fminf(smn[t], smn[t + s]); smx[t] = fmaxf(smx[t], smx[t + s]); }
        __syncthreads();
    }
    if (t == 0) { pmn[blockIdx.x] = smn[0]; pmx[blockIdx.x] = smx[0]; }
}

// Fold 1024 partials per image -> mnf/mxf.
__global__ void k_reduce(const float* __restrict__ pmn, const float* __restrict__ pmx,
                         float* __restrict__ mnf, float* __restrict__ mxf) {
    __shared__ float smn[256];
    __shared__ float smx[256];
    int b = blockIdx.x, t = threadIdx.x;
    float lmn = INFINITY, lmx = -INFINITY;
    for (int j = t; j < 1024; j += 256) {
        lmn = fminf(lmn, pmn[b * 1024 + j]);
        lmx = fmaxf(lmx, pmx[b * 1024 + j]);
    }
    smn[t] = lmn; smx[t] = lmx;
    __syncthreads();
    for (int s = 128; s > 0; s >>= 1) {
        if (t < s) { smn[t] = fminf(smn[t], smn[t + s]); smx[t] = fmaxf(smx[t], smx[t + s]); }
        __syncthreads();
    }
    if (t == 0) { mnf[b] = smn[0]; mxf[b] = smx[0]; }
}

// Normalize + border mask -> final saliency (d_out), fused with hist round 1.
__global__ void k_norm_hist(const float* __restrict__ in, const float* __restrict__ mnf,
                            const float* __restrict__ mxf, float* __restrict__ out,
                            unsigned int* __restrict__ g) {
    __shared__ unsigned int h[4096];
    int t = threadIdx.x;
    int b = blockIdx.x >> 5;
    int base = b * HW + (blockIdx.x & 31) * 8192;
    float mn = mnf[b], mx = mxf[b];
    float inv = 1.0f / (mx - mn + 1e-8f);
    for (int i = t; i < 4096; i += 256) h[i] = 0u;
    __syncthreads();
    for (int j = 0; j < 32; ++j) {
        int idx = base + j * 256 + t;
        float v = (in[idx] - mn) * inv;
        int xx = idx & 511, yy = (idx >> 9) & 511;
        bool inside = (xx >= 12) && (xx < 500) && (yy >= 12) && (yy < 500);
        v = inside ? v : 0.0f;
        out[idx] = v;
        atomicAdd(&h[__float_as_uint(v) >> 20], 1u);
    }
    __syncthreads();
    unsigned int* gb = g + b * 4096;
    for (int i = t; i < 4096; i += 256)
        if (h[i]) atomicAdd(&gb[i], h[i]);
}

// ---------------------------------------------------------------------------
// Parallel 3-round radix select (bits 12/12/8) for BOTH k=26214 (threshold)
// and k=80 (candidate cutoff), sharing the same histogram passes.
// ---------------------------------------------------------------------------

__global__ void k_hist2(const float* __restrict__ sal,
                        const unsigned int* __restrict__ prefA,
                        const unsigned int* __restrict__ prefB,
                        unsigned int* __restrict__ gA, unsigned int* __restrict__ gB) {
    __shared__ unsigned int hA[4096];
    __shared__ unsigned int hB[4096];
    int t = threadIdx.x;
    int b = blockIdx.x >> 5;
    int start = (blockIdx.x & 31) * 8192;
    const float* p = sal + (size_t)b * HW;
    unsigned int pA = prefA[b], pB = prefB[b];
    for (int i = t; i < 4096; i += 256) { hA[i] = 0u; hB[i] = 0u; }
    __syncthreads();
    for (int j = 0; j < 32; ++j) {
        unsigned int u = __float_as_uint(p[start + j * 256 + t]);
        unsigned int hi = u >> 20, mid = (u >> 8) & 4095u;
        if (hi == pA) atomicAdd(&hA[mid], 1u);
        if (hi == pB) atomicAdd(&hB[mid], 1u);
    }
    __syncthreads();
    unsigned int* ga = gA + b * 4096;
    unsigned int* gb2 = gB + b * 4096;
    for (int i = t; i < 4096; i += 256) {
        if (hA[i]) atomicAdd(&ga[i], hA[i]);
        if (hB[i]) atomicAdd(&gb2[i], hB[i]);
    }
}

__global__ void k_hist3(const float* __restrict__ sal,
                        const unsigned int* __restrict__ prefA,
                        const unsigned int* __restrict__ prefB,
                        unsigned int* __restrict__ gA, unsigned int* __restrict__ gB) {
    __shared__ unsigned int hA[256];
    __shared__ unsigned int hB[256];
    int t = threadIdx.x;
    int b = blockIdx.x >> 5;
    int start = (blockIdx.x & 31) * 8192;
    const float* p = sal + (size_t)b * HW;
    unsigned int pA = prefA[b], pB = prefB[b];
    hA[t] = 0u; hB[t] = 0u;
    __syncthreads();
    for (int j = 0; j < 32; ++j) {
        unsigned int u = __float_as_uint(p[start + j * 256 + t]);
        unsigned int hi = u >> 8, lo = u & 255u;
        if (hi == pA) atomicAdd(&hA[lo], 1u);
        if (hi == pB) atomicAdd(&hB[lo], 1u);
    }
    __syncthreads();
    unsigned int* ga = gA + b * 256;
    unsigned int* gb2 = gB + b * 256;
    if (hA[t]) atomicAdd(&ga[t], hA[t]);
    if (hB[t]) atomicAdd(&gb2[t], hB[t]);
}

// Find bin d (from top) s.t. suffix count crosses krem.
__device__ void radix_step(const unsigned int* __restrict__ h, int nbins, int krem,
                           int t, unsigned int* tsum, int* sbin, int* skrem) {
    int bpt = nbins >> 8;
    unsigned int s = 0;
    for (int j = 0; j < bpt; ++j) s += h[t * bpt + j];
    tsum[t] = s;
    __syncthreads();
    if (t == 0) {
        unsigned int cum = 0; int seg = 0;
        for (int d = 255; d >= 0; --d) {
            unsigned int c2 = cum + tsum[d];
            if ((int)c2 >= krem) { seg = d; break; }
            cum = c2;
        }
        unsigned int c = cum;
        for (int j = bpt - 1; j >= 0; --j) {
            unsigned int hv = h[seg * bpt + j];
            if ((int)(c + hv) >= krem) { *sbin = seg * bpt + j; *skrem = krem - (int)c; break; }
            c += hv;
        }
    }
    __syncthreads();
}

__global__ void k_scan1(const unsigned int* __restrict__ g,
                        unsigned int* prefA, int* kremA, unsigned int* prefB, int* kremB) {
    __shared__ unsigned int tsum[256];
    __shared__ int sbin, skrem;
    int b = blockIdx.x, t = threadIdx.x;
    radix_step(g + b * 4096, 4096, KSEL, t, tsum, &sbin, &skrem);
    if (t == 0) { prefA[b] = (unsigned int)sbin; kremA[b] = skrem; }
    __syncthreads();
    radix_step(g + b * 4096, 4096, MCAND, t, tsum, &sbin, &skrem);
    if (t == 0) { prefB[b] = (unsigned int)sbin; kremB[b] = skrem; }
}

__global__ void k_scan2(const unsigned int* __restrict__ gA, const unsigned int* __restrict__ gB,
                        unsigned int* prefA, int* kremA, unsigned int* prefB, int* kremB) {
    __shared__ unsigned int tsum[256];
    __shared__ int sbin, skrem;
    int b = blockIdx.x, t = threadIdx.x;
    radix_step(gA + b * 4096, 4096, kremA[b], t, tsum, &sbin, &skrem);
    if (t == 0) { prefA[b] = (prefA[b] << 12) | (unsigned int)sbin; kremA[b] = skrem; }
    __syncthreads();
    radix_step(gB + b * 4096, 4096, kremB[b], t, tsum, &sbin, &skrem);
    if (t == 0) { prefB[b] = (prefB[b] << 12) | (unsigned int)sbin; kremB[b] = skrem; }
}

__global__ void k_scan3(const unsigned int* __restrict__ gA, const unsigned int* __restrict__ gB,
                        const unsigned int* prefA, const int* kremA,
                        const unsigned int* prefB, const int* kremB,
                        unsigned int* __restrict__ ucut) {
    __shared__ unsigned int tsum[256];
    __shared__ int sbin, skrem;
    __shared__ unsigned int thrbits;
    int b = blockIdx.x, t = threadIdx.x;
    radix_step(gA + b * 256, 256, kremA[b], t, tsum, &sbin, &skrem);
    if (t == 0) {
        unsigned int kth = (prefA[b] << 8) | (unsigned int)sbin;
        float thr = fmaxf(__uint_as_float(kth), 0.1f);
        thrbits = __float_as_uint(thr);
    }
    __syncthreads();
    radix_step(gB + b * 256, 256, kremB[b], t, tsum, &sbin, &skrem);
    if (t == 0) {
        unsigned int c80 = (prefB[b] << 8) | (unsigned int)sbin;
        ucut[b] = (c80 > thrbits) ? c80 : thrbits;   // uint order == float order (>=0)
    }
}

__global__ void k_collect(const float* __restrict__ sal, const unsigned int* __restrict__ ucut,
                          float* __restrict__ candv, int* __restrict__ candi,
                          int* __restrict__ ccnt) {
    int t = threadIdx.x;
    int b = blockIdx.x >> 5;
    int start = (blockIdx.x & 31) * 8192;
    const float* p = sal + (size_t)b * HW;
    unsigned int cut = ucut[b];
    for (int j = 0; j < 32; ++j) {
        int i = start + j * 256 + t;
        unsigned int u = __float_as_uint(p[i]);
        if (u >= cut) {
            int pos = atomicAdd(&ccnt[b], 1);
            if (pos < CAP) { candv[b * CAP + pos] = p[i]; candi[b * CAP + pos] = i; }
        }
    }
}

// Rank (value desc, index asc — lax.top_k tie rule), bitmask greedy NMS.
// No runtime-indexed thread-local arrays anywhere (they'd go to scratch).
__global__ void k_final(const float* __restrict__ candv, const int* __restrict__ candi,
                        const int* __restrict__ ccnt, float* __restrict__ out) {
    __shared__ float cval[CAP];
    __shared__ int   cidx[CAP];
    __shared__ int   si[MCAND];
    __shared__ float sx[MCAND];
    __shared__ float sy[MCAND];
    __shared__ unsigned long long nearLo[MCAND];
    __shared__ unsigned long long nearHi[MCAND];
    int b = blockIdx.x, t = threadIdx.x;
    int n = min(ccnt[b], CAP);
    for (int i = t; i < n; i += 256) { cval[i] = candv[b * CAP + i]; cidx[i] = candi[b * CAP + i]; }
    __syncthreads();
    int m = min(n, MCAND);
    // rank by (value desc, index asc)
    for (int i = t; i < n; i += 256) {
        float vi = cval[i]; int ii = cidx[i];
        int rank = 0;
        for (int j = 0; j < n; j++) {
            float vj = cval[j];
            if (vj > vi || (vj == vi && cidx[j] < ii)) rank++;
        }
        if (rank < MCAND) si[rank] = ii;
    }
    __syncthreads();
    for (int i = t; i < m; i += 256) {
        sx[i] = (float)(si[i] & 511);
        sy[i] = (float)(si[i] >> 9);
    }
    __syncthreads();
    // pairwise proximity masks (parallel)
    for (int i = t; i < m; i += 256) {
        unsigned long long lo = 0ull, hi = 0ull;
        float x = sx[i], y = sy[i];
        for (int j = 0; j < m; j++) {
            float dx = sx[j] - x, dy = sy[j] - y;
            if (dx * dx + dy * dy < 100.0f) {
                if (j < 64) lo |= (1ull << j);
                else        hi |= (1ull << (j - 64));
            }
        }
        nearLo[i] = lo; nearHi[i] = hi;
    }
    __syncthreads();
    // greedy pass (thread 0, registers only)
    if (t == 0) {
        unsigned long long kLo = 0ull, kHi = 0ull;
        int cnt = 0;
        for (int i = 0; i < m; i++) {
            bool near_kept = ((nearLo[i] & kLo) | (nearHi[i] & kHi)) != 0ull;
            if (!near_kept) {
                out[b * 10 + 2 * cnt]     = sx[i];
                out[b * 10 + 2 * cnt + 1] = sy[i];
                out[160 + b * 5 + cnt]    = 1.0f;
                if (i < 64) kLo |= (1ull << i); else kHi |= (1ull << (i - 64));
                cnt++;
                if (cnt == TOPK) break;
            }
        }
        for (int j = cnt; j < TOPK; j++) {
            out[b * 10 + 2 * j]     = -1.0f;
            out[b * 10 + 2 * j + 1] = -1.0f;
            out[160 + b * 5 + j]    = -1.0f;
        }
    }
}

extern "C" void kernel_launch(void* const* d_in, const int* in_sizes, int n_in,
                              void* d_out, int out_size, void* d_ws, size_t ws_size,
                              hipStream_t stream) {
    const float* img = (const float*)d_in[0];
    float* out = (float*)d_out;
    char* ws = (char*)d_ws;

    // ws layout (bytes):
    //   [0, 32M)   : A (complex). Dead after k_mag_hblur. Then reused:
    //                  [0, ~1.1M) hists + ccnt + cand   (memset after vblur)
    //                  [20M, 20M+128K) pmn/pmx partials (written by vblur)
    //   [32M, 64M) : Bc (complex). Dead after transpose #2. Then:
    //                  [32M, 48M) hb (h-blurred saliency)
    //   [48M, 64M) : salb (v-blurred)
    //   [64M, +448): scalar stats
    float2* A   = (float2*)ws;
    float2* Bc  = (float2*)(ws + 33554432UL);
    float*  hb  = (float*)(ws + 33554432UL);
    float*  salb = (float*)(ws + 50331648UL);

    unsigned int* hist1  = (unsigned int*)(ws + 0UL);        // 16*4096 u32 = 256KB
    unsigned int* hist2a = (unsigned int*)(ws + 262144UL);   // 256KB
    unsigned int* hist2b = (unsigned int*)(ws + 524288UL);   // 256KB
    unsigned int* hist3a = (unsigned int*)(ws + 786432UL);   // 16KB
    unsigned int* hist3b = (unsigned int*)(ws + 802816UL);   // 16KB
    int*          ccnt   = (int*)(ws + 819200UL);            // 64B
    const size_t  ZEROBYTES = 819264UL;
    float*        candv  = (float*)(ws + 851968UL);          // 128KB
    int*          candi  = (int*)(ws + 983040UL);            // 128KB

    float* pmn = (float*)(ws + 20971520UL);                  // 64KB (16384 f32)
    float* pmx = (float*)(ws + 21037056UL);                  // 64KB

    char* stats = ws + 67108864UL;
    unsigned int* prefA = (unsigned int*)(stats + 0);
    int*          kremA = (int*)(stats + 64);
    unsigned int* prefB = (unsigned int*)(stats + 128);
    int*          kremB = (int*)(stats + 192);
    unsigned int* ucut  = (unsigned int*)(stats + 256);
    float*        mnf   = (float*)(stats + 320);
    float*        mxf   = (float*)(stats + 384);

    float* salout = out + 240;   // sal region of d_out

    k_win_rowfft<<<dim3(8192), dim3(256), 0, stream>>>(img, A);
    k_transpose<<<dim3(16, 16, 16), dim3(32, 8), 0, stream>>>(A, Bc);
    k_phase<<<dim3(8192), dim3(256), 0, stream>>>(Bc);                 // fwd-H + phase + inv-H
    k_transpose<<<dim3(16, 16, 16), dim3(32, 8), 0, stream>>>(Bc, A);
    k_mag_hblur<<<dim3(8192), dim3(256), 0, stream>>>(A, hb);          // inv-W + |.|^2 + hblur
    k_vblur<<<dim3(16384), dim3(256), 0, stream>>>(hb, salb, pmn, pmx);
    hipMemsetAsync(ws, 0, ZEROBYTES, stream);                          // hists + ccnt (A dead)
    k_reduce<<<dim3(BATCH), dim3(256), 0, stream>>>(pmn, pmx, mnf, mxf);
    k_norm_hist<<<dim3(512), dim3(256), 0, stream>>>(salb, mnf, mxf, salout, hist1);
    k_scan1<<<dim3(BATCH), dim3(256), 0, stream>>>(hist1, prefA, kremA, prefB, kremB);
    k_hist2<<<dim3(512), dim3(256), 0, stream>>>(salout, prefA, prefB, hist2a, hist2b);
    k_scan2<<<dim3(BATCH), dim3(256), 0, stream>>>(hist2a, hist2b, prefA, kremA, prefB, kremB);
    k_hist3<<<dim3(512), dim3(256), 0, stream>>>(salout, prefA, prefB, hist3a, hist3b);
    k_scan3<<<dim3(BATCH), dim3(256), 0, stream>>>(hist3a, hist3b, prefA, kremA, prefB, kremB, ucut);
    k_collect<<<dim3(512), dim3(256), 0, stream>>>(salout, ucut, candv, candi, ccnt);
    k_final<<<dim3(BATCH), dim3(256), 0, stream>>>(candv, candi, ccnt, out);
}